// Round 9
// baseline (288.230 us; speedup 1.0000x reference)
//
#include <hip/hip_runtime.h>
#include <hip/hip_bf16.h>
#include <stdint.h>

// VQ nearest-codebook: B=8,N=4096,C=256,K=8192
// R17 = R14 structure (barrier-free, per-wave private B, A in LDS) with the
// VALU pipe attacked (VALUBusy*dur ~83us > MFMA floor ~62us across R8-R16):
//  (1) staging addresses strength-reduced: 4 persistent 32-bit voffsets,
//      +64B/step, +130624B at tile wrap (compile-time deltas, unrolled ks);
//  (2) A ds_reads: one base + offset immediates (0/8192/16384/24576);
//      B ds_reads: 2 precomputed ring bases + nf*1024 immediates (0 VALU);
//  (3) v_med3_u32 insert: k2'=med3(k1,k2,key) == min(k2,max(k1,key)) for
//      k1<=k2 (identity verified incl. INF-init) - saves 1 op x 2048/wave;
//  (4) ring-2 stage-FIRST + counted WAITV(4) (certify B(t), keep B(t+1)):
//      kills R14's per-step vmcnt(0) drain. WAITV(8) at ks0/ks7 windows
//      (cq batch), 0 at tail. Compiler-barrier pins fix the FIFO order.
//  (5) per-wave B stride 8224B (+8 banks/wave) to cut cross-wave conflicts.
// No skew (R16 falsified convoy theory). Math/output identical to verified
// R10-R16 (absmax=0 throughout).

#define M_ROWS 32768   // B*N
#define KCODES 8192
#define CDIM   256
#define BM 128         // rows per block
#define BNT 256        // codes per tile
#define BK 32
#define NTILES 32      // KCODES / BNT
#define NREC 32        // records per row (each = top-2 over a 256-code subset)
#define MARGIN 0.75f   // >> hi-GEMM err (~0.32) + 2x key quantization (0.125)

typedef _Float16 f16x8 __attribute__((ext_vector_type(8)));
typedef _Float16 f16x4 __attribute__((ext_vector_type(4)));
typedef float    f32x4 __attribute__((ext_vector_type(4)));

#define WAITV(N) asm volatile("s_waitcnt vmcnt(" #N ")" ::: "memory")
#define CPIN()   asm volatile("" ::: "memory")

__device__ __forceinline__ unsigned umin2(unsigned a, unsigned b) { return a < b ? a : b; }
__device__ __forceinline__ unsigned umed3(unsigned a, unsigned b, unsigned c) {
  unsigned d;
  asm("v_med3_u32 %0, %1, %2, %3" : "=v"(d) : "v"(a), "v"(b), "v"(c));
  return d;
}

// ---------------- prep: fp16 hi (scaled by 64) + row sq-norms ----------------
__global__ void vq_prep(const float* __restrict__ x, const float* __restrict__ cb,
                        _Float16* __restrict__ xhi, _Float16* __restrict__ cbhi,
                        float* __restrict__ xsq, float* __restrict__ cbsq) {
  const int wave = threadIdx.x >> 6, lane = threadIdx.x & 63;
  const int row = blockIdx.x * 4 + wave;     // one wave per row
  const float* src;
  _Float16* dhi;
  float* dsq;
  if (row < M_ROWS) {
    src = x + (size_t)row * CDIM;  dhi = xhi + (size_t)row * CDIM;  dsq = xsq + row;
  } else {
    const int r = row - M_ROWS;
    src = cb + (size_t)r * CDIM;   dhi = cbhi + (size_t)r * CDIM;   dsq = cbsq + r;
  }
  const float4 v = *(const float4*)(src + lane * 4);
  f16x4 h;
  h[0] = (_Float16)(v.x * 64.0f); h[1] = (_Float16)(v.y * 64.0f);
  h[2] = (_Float16)(v.z * 64.0f); h[3] = (_Float16)(v.w * 64.0f);
  *(f16x4*)(dhi + lane * 4) = h;
  float s = v.x * v.x + v.y * v.y + v.z * v.z + v.w * v.w;
  #pragma unroll
  for (int off = 32; off > 0; off >>= 1) s += __shfl_down(s, off, 64);
  if (lane == 0) *dsq = s;
}

// ---------------- pass1: A-resident hi GEMM + top-2 int-key records ----------------
__device__ __forceinline__ void gl16p(const void* g, void* l) {
  __builtin_amdgcn_global_load_lds(
      (const __attribute__((address_space(1))) unsigned int*)g,
      (__attribute__((address_space(3))) unsigned int*)l, 16, 0, 0);
}

__global__ __launch_bounds__(512) void vq_pass1(
    const _Float16* __restrict__ xhi, const _Float16* __restrict__ cbhi,
    const float* __restrict__ cbsqg, uint2* __restrict__ srec) {
  extern __shared__ char smem[];
  _Float16* sA = (_Float16*)smem;             // 128 x 256 fp16 = 64 KB (shared, RO)
  char* sBb = smem + 65536;                   // 8 waves x (2x4096B + 32B pad) = 65792 B

  const int tid  = threadIdx.x;
  const int wave = tid >> 6, lane = tid & 63;
  const int quad = lane >> 4, l15 = lane & 15;
  const int mbase = blockIdx.x * BM;
  const int wrow = (wave >> 2) * 64;    // row half
  const int q    = wave & 3;            // col quarter
  const int wcol = q * 64;

  // ---- stage A once (8 gl16/wave); must complete before the barrier.
  {
    const int ar = lane >> 5;            // row within pair
    const int as = lane & 31;            // 16B slot
    #pragma unroll
    for (int t = 0; t < 8; ++t) {
      const int rb  = (wave * 8 + t) * 2;
      const int row = rb + ar;
      const int slot = as ^ (row & 7);
      gl16p(xhi + (size_t)(mbase + row) * CDIM + slot * 8, sA + rb * CDIM);
    }
  }
  CPIN();   // pin A loads oldest in the vmcnt FIFO

  // B staging geometry (R2's measured-zero-conflict pattern): row stride 64B.
  const int srl  = lane >> 2;
  const int scol = (((lane & 3) ^ ((lane >> 3) & 3)) << 3);
  const int fcol = ((quad ^ ((l15 >> 1) & 3)) << 3);
  const int asw  = l15 & 7;             // A frag de-swizzle

  char* sBw = sBb + wave * 8224;        // private ring-2; +32B/wave bank decorrelation

  // staging source voffsets (bytes from cbhi) for the 4 gl16s of a stage;
  // advanced by compile-time deltas (+64 per k-step, +130624 at tile wrap).
  unsigned v0 = (unsigned)((wcol +  0 + srl) * 512 + scol * 2);
  unsigned v1 = v0 + 16 * 512;
  unsigned v2 = v0 + 32 * 512;
  unsigned v3 = v0 + 48 * 512;

  auto stage4 = [&](int buf) {
    char* dst = sBw + buf * 4096;
    const char* base = (const char*)cbhi;
    gl16p(base + v0, dst);
    gl16p(base + v1, dst + 1024);
    gl16p(base + v2, dst + 2048);
    gl16p(base + v3, dst + 3072);
  };

  // prologue: stage B(0,0); cq0; certify A; barrier (the only barrier).
  stage4(0);
  CPIN();
  float cq_cur[4], cq_nxt[4];
  #pragma unroll
  for (int j = 0; j < 4; ++j) cq_cur[j] = cbsqg[wcol + j * 16 + l15];
  CPIN();
  WAITV(8);                       // retire A(8); leave B0(4)+cq(4)
  __builtin_amdgcn_s_barrier();
  CPIN();
  v0 += 64; v1 += 64; v2 += 64; v3 += 64;   // -> (0,1)

  // precomputed read bases
  const char* sArow = (const char*)sA + (wrow + l15) * 512;  // + aoff + mf*8192
  const char* bB0 = sBw + l15 * 64 + fcol * 2;               // ring slot 0
  const char* bB1 = bB0 + 4096;                              // ring slot 1

  unsigned k1[4][4], k2[4][4];

  for (int nt = 0; nt < NTILES; ++nt) {
    const bool lastnt = (nt == NTILES - 1);
    if ((nt & 3) == 0) {   // open subchunk (4 nt x 64 cols = 256 codes / record)
      #pragma unroll
      for (int mf = 0; mf < 4; ++mf)
        #pragma unroll
        for (int i = 0; i < 4; ++i) { k1[mf][i] = 0x7fffffffu; k2[mf][i] = 0x7fffffffu; }
    }

    f32x4 acc[4][4];
    #pragma unroll
    for (int mf = 0; mf < 4; ++mf)
      #pragma unroll
      for (int nf = 0; nf < 4; ++nf) {
        f32x4 z = {0.0f, 0.0f, 0.0f, 0.0f};
        acc[mf][nf] = z;
      }

    #pragma unroll
    for (int ks = 0; ks < 8; ++ks) {
      // ---- stage slot: stage B(t+1) into buf (t+1)&1 (that buffer's last
      // reads finished during compute(t-1), program-order safe per wave).
      if (ks < 7) {
        stage4((ks + 1) & 1);
        if (ks == 6) { v0 += 130624; v1 += 130624; v2 += 130624; v3 += 130624; }
        else         { v0 += 64;     v1 += 64;     v2 += 64;     v3 += 64;     }
      } else if (!lastnt) {
        stage4(0);
        CPIN();
        #pragma unroll
        for (int j = 0; j < 4; ++j)
          cq_nxt[j] = cbsqg[(nt + 1) * BNT + wcol + j * 16 + l15];
        v0 += 64; v1 += 64; v2 += 64; v3 += 64;
      }
      // ---- counted certify of B(t). FIFO windows (audited):
      // ks0: {B(t), cq, B(t+1)} -> 8 ; ks1: {cq, B(t), B(t+1)} -> 4 (cq old)
      // ks2-6: {B(t), B(t+1)} -> 4 ; ks7: {B(t), B(t+1), cq} -> 8 ; tail -> 0
      if (ks == 0)       WAITV(8);
      else if (ks < 7)   WAITV(4);
      else if (!lastnt)  WAITV(8);
      else               WAITV(0);
      CPIN();

      // ---- compute step t from ring slot ks&1
      const int aoff = (((ks * 4 + quad) ^ asw) << 4);
      const char* ab = sArow + aoff;
      f16x8 ah0 = *(const f16x8*)(ab);
      f16x8 ah1 = *(const f16x8*)(ab + 8192);
      f16x8 ah2 = *(const f16x8*)(ab + 16384);
      f16x8 ah3 = *(const f16x8*)(ab + 24576);
      const char* bb = (ks & 1) ? bB1 : bB0;
      __builtin_amdgcn_s_setprio(1);
      #pragma unroll
      for (int nf = 0; nf < 4; ++nf) {
        const f16x8 bh = *(const f16x8*)(bb + nf * 1024);
        acc[0][nf] = __builtin_amdgcn_mfma_f32_16x16x32_f16(ah0, bh, acc[0][nf], 0, 0, 0);
        acc[1][nf] = __builtin_amdgcn_mfma_f32_16x16x32_f16(ah1, bh, acc[1][nf], 0, 0, 0);
        acc[2][nf] = __builtin_amdgcn_mfma_f32_16x16x32_f16(ah2, bh, acc[2][nf], 0, 0, 0);
        acc[3][nf] = __builtin_amdgcn_mfma_f32_16x16x32_f16(ah3, bh, acc[3][nf], 0, 0, 0);
      }
      __builtin_amdgcn_s_setprio(0);
    }

    // int-key top-2 insert: key = (uint)(16*v + 32768) << 13 | col
    // v = cbsq - 2*dot; acc = 4096*dot => 16*v = (16*cbsq+32768) - acc/128
    // k2' = med3(k1,k2,key) == min(k2, max(k1,key)) given k1<=k2 invariant.
    #pragma unroll
    for (int nf = 0; nf < 4; ++nf) {
      const int col = nt * BNT + wcol + nf * 16 + l15;   // global code (C/D: col = lane&15)
      const float cq16 = fmaf(cq_cur[nf], 16.0f, 32768.0f);
      #pragma unroll
      for (int mf = 0; mf < 4; ++mf)
        #pragma unroll
        for (int i = 0; i < 4; ++i) {
          const float kf = fmaf(acc[mf][nf][i], -0.0078125f, cq16);
          const unsigned key = ((unsigned)kf << 13) | (unsigned)col;
          k2[mf][i] = umed3(k1[mf][i], k2[mf][i], key);
          k1[mf][i] = umin2(k1[mf][i], key);
        }
    }

    if ((nt & 3) == 3) {   // close subchunk: 16-lane top-2 butterfly merge, store record
      const int g = (nt >> 2) * 4 + q;              // 0..31
      #pragma unroll
      for (int mf = 0; mf < 4; ++mf)
        #pragma unroll
        for (int i = 0; i < 4; ++i) {
          unsigned a1 = k1[mf][i], a2 = k2[mf][i];
          #pragma unroll
          for (int m = 1; m <= 8; m <<= 1) {
            const unsigned o1 = (unsigned)__shfl_xor((int)a1, m, 64);
            const unsigned o2 = (unsigned)__shfl_xor((int)a2, m, 64);
            a2 = umin2(umin2(a2, o2), umed3(a1, a2, o1));
            a1 = umin2(a1, o1);
          }
          if (l15 == 0) {
            const int rl = wrow + mf * 16 + quad * 4 + i;   // C/D row (0..127)
            uint2 r; r.x = a1; r.y = a2;
            srec[(size_t)(mbase + rl) * NREC + g] = r;
          }
        }
    }

    #pragma unroll
    for (int j = 0; j < 4; ++j) cq_cur[j] = cq_nxt[j];
  }
}

// ---------------- finalize: exact fp32 dots for margin candidates ----------------
__global__ void vq_finalize(const float* __restrict__ x, const float* __restrict__ cb,
                            const float* __restrict__ xsq, const float* __restrict__ cbsq,
                            const uint2* __restrict__ srec,
                            float* __restrict__ outIdx, float* __restrict__ outDist,
                            float* __restrict__ codes) {
  const int wave = threadIdx.x >> 6, lane = threadIdx.x & 63;
  const int row = blockIdx.x * 4 + wave;    // one wave per row
  uint2 rec;
  if (lane < NREC) rec = srec[(size_t)row * NREC + lane];
  else { rec.x = 0x7fffffffu; rec.y = 0x7fffffffu; }
  const float v1 = (float)(rec.x >> 13) * 0.0625f - 2048.0f;
  const float v2 = (float)(rec.y >> 13) * 0.0625f - 2048.0f;
  const int c1 = (int)(rec.x & 8191u);
  const int c2 = (int)(rec.y & 8191u);

  float gm = v1;
  #pragma unroll
  for (int m = 1; m <= 32; m <<= 1) gm = fminf(gm, __shfl_xor(gm, m, 64));
  const float thr = gm + MARGIN;
  unsigned long long mask1 = __ballot(v1 <= thr);
  unsigned long long mask2 = __ballot(v2 <= thr);

  const float4 xv = *(const float4*)(x + (size_t)row * CDIM + lane * 4);
  const float xq = xsq[row];
  float best = __builtin_inff(); int bidx = 1 << 30;

  #pragma unroll
  for (int pass = 0; pass < 2; ++pass) {
    unsigned long long m = pass ? mask2 : mask1;
    const int fi = pass ? c2 : c1;
    while (m) {
      const int g = __builtin_ctzll((long long)m); m &= m - 1;
      const int ci = __shfl(fi, g, 64);
      const float4 cv = *(const float4*)(cb + (size_t)ci * CDIM + lane * 4);
      float s = xv.x * cv.x + xv.y * cv.y + xv.z * cv.z + xv.w * cv.w;
      #pragma unroll
      for (int mm = 1; mm <= 32; mm <<= 1) s += __shfl_xor(s, mm, 64);
      const float dist = xq + cbsq[ci] - 2.0f * s;
      if (dist < best || (dist == best && ci < bidx)) { best = dist; bidx = ci; }
    }
  }

  if (lane == 0) { outIdx[row] = (float)bidx; outDist[row] = best; }
  const float4 cw = *(const float4*)(cb + (size_t)bidx * CDIM + lane * 4);
  *(float4*)(codes + (size_t)row * CDIM + lane * 4) = cw;
}

extern "C" void kernel_launch(void* const* d_in, const int* in_sizes, int n_in,
                              void* d_out, int out_size, void* d_ws, size_t ws_size,
                              hipStream_t stream) {
  const float* x  = (const float*)d_in[0];   // [8,4096,256] fp32
  const float* cb = (const float*)d_in[1];   // [8192,256] fp32
  float* out = (float*)d_out;                // codes | idx | dist

  char* w = (char*)d_ws;                     // ~29.2 MB
  _Float16* xhi  = (_Float16*)(w);                 // 16 MB
  _Float16* cbhi = (_Float16*)(w + 16777216);      //  4 MB
  float*    xsq  = (float*)   (w + 20971520);      // 128 KB
  float*    cbsq = (float*)   (w + 21102592);      //  32 KB
  uint2*    srec = (uint2*)   (w + 21135360);      //  8 MB (32768*32*8B)

  vq_prep<<<(M_ROWS + KCODES) / 4, 256, 0, stream>>>(x, cb, xhi, cbhi, xsq, cbsq);
  const size_t smem = 65536 + 65792;  // A 64K + padded private B ring-2 = 131328 B
  vq_pass1<<<dim3(M_ROWS / BM), 512, smem, stream>>>(xhi, cbhi, cbsq, srec);
  vq_finalize<<<M_ROWS / 4, 256, 0, stream>>>(x, cb, xsq, cbsq, srec,
                                              out + 8388608, out + 8421376, out);
}